// Round 9
// baseline (12271.322 us; speedup 1.0000x reference)
//
#include <hip/hip_runtime.h>
#include <hip/hip_bf16.h>
#include <math.h>

// RSSM scan, MI355X. ZERO-SYNC (R7/R8-proven) + R9: 1024-thread scan blocks
// (16 waves = 4/SIMD, 2x MLP vs R8) and software-pipelined B-prefetch in ALL
// stage GEMMs (ping-pong register buffers). 32 blocks x 16 batch rows,
// intermediates in LDS, no barriers/fences. Weights fragment-packed, GRU
// no-pad (17.8 MB/step). D=1024 Z=256 A=32 H=512 E=1024, T=64, B=512.

using bf16 = __hip_bfloat16;
using short8 = __attribute__((ext_vector_type(8))) short;
using f32x4 = __attribute__((ext_vector_type(4))) float;

__device__ __forceinline__ float sp_f(float x){ return x > 15.f ? x : log1pf(__expf(x)); }
__device__ __forceinline__ float sg_f(float x){ return 1.f/(1.f+__expf(-x)); }
__device__ __forceinline__ float b2f(bf16 x){ return __bfloat162float(x); }
__device__ __forceinline__ bf16  f2b(float x){ return __float2bfloat16(x); }

// A-LDS swizzled layout (elem index)
__device__ __forceinline__ int aoff(int r, int c, int ldk) {
  return r*ldk + (c & ~63) + ((((c>>3)&7) ^ (r&7))<<3) + (c&7);
}

// NF-frag GEMM, software-pipelined B-prefetch (KC must be even)
template<int NF, int KC, typename AR>
__device__ __forceinline__ void gemmN(f32x4 acc[NF], const bf16* __restrict__ wpf,
                                      int lane, AR aread) {
  short8 b0[NF], b1[NF];
#pragma unroll
  for (int s = 0; s < NF; ++s)
    b0[s] = *(const short8*)(wpf + ((size_t)s*KC)*512 + lane*8);
#pragma unroll 1
  for (int kc = 0; kc < KC; kc += 2) {
#pragma unroll
    for (int s = 0; s < NF; ++s)
      b1[s] = *(const short8*)(wpf + ((size_t)s*KC + kc + 1)*512 + lane*8);
    short8 a = aread(kc*32);
#pragma unroll
    for (int s = 0; s < NF; ++s)
      asm("v_mfma_f32_16x16x32_bf16 %0, %1, %2, %0" : "+v"(acc[s]) : "v"(a), "v"(b0[s]));
    if (kc + 2 < KC) {
#pragma unroll
      for (int s = 0; s < NF; ++s)
        b0[s] = *(const short8*)(wpf + ((size_t)s*KC + kc + 2)*512 + lane*8);
    }
    a = aread((kc+1)*32);
#pragma unroll
    for (int s = 0; s < NF; ++s)
      asm("v_mfma_f32_16x16x32_bf16 %0, %1, %2, %0" : "+v"(acc[s]) : "v"(a), "v"(b1[s]));
  }
}

struct SP {
  const float *prev_state, *prev_belief, *actions, *nonterm, *nb, *nq;
  const bf16 *w_sa, *w_gru, *w_eb, *w_bq, *w_ebq, *w_sq;
  const float *bg, *b_sa, *b_eb, *b_bq, *b_sq;
  const bf16 *obs_c;
  float *o_bel, *o_qst, *o_qm, *o_qsd;
};

__global__ __launch_bounds__(1024) void scan_k(SP p) {
  __shared__ bf16 sB[16*1024];   // bel carry
  __shared__ bf16 sD[16*1024];   // deter; after GRU: sh (0-511) + shq (512-1023)
  __shared__ bf16 sR[16*1024];   // qsa [16][320]; then rnn
  const int tid = threadIdx.x, l = tid & 63, w3 = tid >> 6;   // 16 waves
  const int fl = l & 15, fg = l >> 4;
  const int rbase = blockIdx.x * 16;

  // ---- prologue: bel <- prev_belief ; qsa <- prev_state ; pad zeros once ----
  if (tid < 256) {
    const int r = tid >> 4;
    const int c0 = (tid & 15) * 64;
    const float* src = p.prev_belief + (size_t)(rbase + r)*1024 + c0;
#pragma unroll
    for (int s = 0; s < 8; ++s) {
      float4 a = *(const float4*)(src + s*8);
      float4 b = *(const float4*)(src + s*8 + 4);
      bf16 t8[8] __attribute__((aligned(16)));
      t8[0]=f2b(a.x); t8[1]=f2b(a.y); t8[2]=f2b(a.z); t8[3]=f2b(a.w);
      t8[4]=f2b(b.x); t8[5]=f2b(b.y); t8[6]=f2b(b.z); t8[7]=f2b(b.w);
      *(short8*)(sB + aoff(r, c0 + s*8, 1024)) = *(const short8*)t8;
    }
    const int c1 = (tid & 15) * 16;
    const float* sq2 = p.prev_state + (size_t)(rbase + r)*256 + c1;
#pragma unroll
    for (int s = 0; s < 2; ++s) {
      float4 a = *(const float4*)(sq2 + s*8);
      float4 b = *(const float4*)(sq2 + s*8 + 4);
      bf16 t8[8] __attribute__((aligned(16)));
      t8[0]=f2b(a.x); t8[1]=f2b(a.y); t8[2]=f2b(a.z); t8[3]=f2b(a.w);
      t8[4]=f2b(b.x); t8[5]=f2b(b.y); t8[6]=f2b(b.z); t8[7]=f2b(b.w);
      *(short8*)(sR + aoff(r, c1 + s*8, 320)) = *(const short8*)t8;
    }
  } else if (tid < 320) {
    const int r = (tid-256) >> 2, c0 = 288 + ((tid-256)&3)*8;
    bf16 z8[8] __attribute__((aligned(16))) = {};
    *(short8*)(sR + aoff(r, c0, 320)) = *(const short8*)z8;   // pad, written once
  }
  __syncthreads();

#pragma unroll 1
  for (int t = 0; t < 64; ++t) {
    // ---- S1 prep: actions -> qsa cols 256..287 ----
    if (tid < 128) {
      const int r = tid >> 3, cc = (tid & 7) * 4;
      float4 a = *(const float4*)(p.actions + (size_t)(t*512 + rbase + r)*32 + cc);
      sR[aoff(r, 256+cc,   320)] = f2b(a.x);
      sR[aoff(r, 256+cc+1, 320)] = f2b(a.y);
      sR[aoff(r, 256+cc+2, 320)] = f2b(a.z);
      sR[aoff(r, 256+cc+3, 320)] = f2b(a.w);
    }
    __syncthreads();
    // ---- S1: deter = relu(qsa @ Wsa' + b_sa), N=1024: 4 frags/wave ----
    {
      auto aq = [&](int c){ return *(const short8*)(sR + aoff(fl, c + fg*8, 320)); };
      f32x4 acc[4] = {};
      const int f0 = w3*4;
      gemmN<4,10>(acc, p.w_sa + (size_t)f0*10*512, l, aq);
#pragma unroll
      for (int q = 0; q < 4; ++q) {
        const int col = (f0+q)*16 + fl;
        const float bv = p.b_sa[col];
#pragma unroll
        for (int rr = 0; rr < 4; ++rr) {
          float v = acc[q][rr] + bv;
          sD[aoff(fg*4+rr, col, 1024)] = f2b(v > 0.f ? v : 0.f);
        }
      }
    }
    __syncthreads();
    // ---- S2: GRU, 6-slot no-pad pack: 4 jt/wave ----
    {
#pragma unroll 1
      for (int jj = 0; jj < 4; ++jj) {
        const int jt = w3*4 + jj;
        const bf16* base = p.w_gru + (size_t)jt*32*6*512 + l*8;
        f32x4 ar_ = {}, az_ = {}, ai_ = {}, ah_ = {};
        short8 b0[6], b1[6];
#pragma unroll
        for (int s = 0; s < 6; ++s) b0[s] = *(const short8*)(base + (size_t)s*512);
#pragma unroll 1
        for (int kc = 0; kc < 32; kc += 2) {
#pragma unroll
          for (int s = 0; s < 6; ++s)
            b1[s] = *(const short8*)(base + (size_t)((kc+1)*6 + s)*512);
          short8 ad = *(const short8*)(sD + aoff(fl, kc*32 + fg*8, 1024));
          short8 ab = *(const short8*)(sB + aoff(fl, kc*32 + fg*8, 1024));
          asm("v_mfma_f32_16x16x32_bf16 %0, %1, %2, %0" : "+v"(ar_) : "v"(ad), "v"(b0[0]));
          asm("v_mfma_f32_16x16x32_bf16 %0, %1, %2, %0" : "+v"(az_) : "v"(ad), "v"(b0[1]));
          asm("v_mfma_f32_16x16x32_bf16 %0, %1, %2, %0" : "+v"(ai_) : "v"(ad), "v"(b0[2]));
          asm("v_mfma_f32_16x16x32_bf16 %0, %1, %2, %0" : "+v"(ar_) : "v"(ab), "v"(b0[3]));
          asm("v_mfma_f32_16x16x32_bf16 %0, %1, %2, %0" : "+v"(az_) : "v"(ab), "v"(b0[4]));
          asm("v_mfma_f32_16x16x32_bf16 %0, %1, %2, %0" : "+v"(ah_) : "v"(ab), "v"(b0[5]));
          if (kc + 2 < 32) {
#pragma unroll
            for (int s = 0; s < 6; ++s)
              b0[s] = *(const short8*)(base + (size_t)((kc+2)*6 + s)*512);
          }
          ad = *(const short8*)(sD + aoff(fl, (kc+1)*32 + fg*8, 1024));
          ab = *(const short8*)(sB + aoff(fl, (kc+1)*32 + fg*8, 1024));
          asm("v_mfma_f32_16x16x32_bf16 %0, %1, %2, %0" : "+v"(ar_) : "v"(ad), "v"(b1[0]));
          asm("v_mfma_f32_16x16x32_bf16 %0, %1, %2, %0" : "+v"(az_) : "v"(ad), "v"(b1[1]));
          asm("v_mfma_f32_16x16x32_bf16 %0, %1, %2, %0" : "+v"(ai_) : "v"(ad), "v"(b1[2]));
          asm("v_mfma_f32_16x16x32_bf16 %0, %1, %2, %0" : "+v"(ar_) : "v"(ab), "v"(b1[3]));
          asm("v_mfma_f32_16x16x32_bf16 %0, %1, %2, %0" : "+v"(az_) : "v"(ab), "v"(b1[4]));
          asm("v_mfma_f32_16x16x32_bf16 %0, %1, %2, %0" : "+v"(ah_) : "v"(ab), "v"(b1[5]));
        }
        const int j = jt*16 + fl;
        const float g0 = p.bg[j], g1 = p.bg[1024+j], g2 = p.bg[2048+j], g3 = p.bg[3072+j];
#pragma unroll
        for (int rr = 0; rr < 4; ++rr) {
          const int row = fg*4 + rr;
          const float r_ = sg_f(ar_[rr] + g0);
          const float z_ = sg_f(az_[rr] + g1);
          const float nn = tanhf((ai_[rr] + g2) + r_*(ah_[rr] + g3));
          const float h = b2f(sB[aoff(row, j, 1024)]);
          sR[aoff(row, j, 1024)] = f2b((1.f - z_)*nn + z_*h);
        }
      }
    }
    __syncthreads();
    // ---- S3: sh = relu(rnn @ Web' + b_eb), N=512: 2 frags/wave ----
    {
      auto ar = [&](int c){ return *(const short8*)(sR + aoff(fl, c + fg*8, 1024)); };
      f32x4 acc[2] = {};
      const int f0 = w3*2;
      gemmN<2,32>(acc, p.w_eb + (size_t)f0*32*512, l, ar);
#pragma unroll
      for (int q = 0; q < 2; ++q) {
        const int col = (f0+q)*16 + fl;
        const float bv = p.b_eb[col];
#pragma unroll
        for (int rr = 0; rr < 4; ++rr) {
          float v = acc[q][rr] + bv;
          sD[aoff(fg*4+rr, col, 1024)] = f2b(v > 0.f ? v : 0.f);
        }
      }
    }
    __syncthreads();
    // ---- S4: belief head (paired Wbq'): 8 frags/wave ----
    {
      auto as = [&](int c){ return *(const short8*)(sD + aoff(fl, c + fg*8, 1024)); };
      const float* nbt = p.nb + (size_t)(t*512 + rbase)*1024;
      float* obt = p.o_bel + (size_t)(t*512 + rbase)*1024;
#pragma unroll 1
      for (int g = 0; g < 2; ++g) {
        f32x4 acc[4] = {};
        const int f0 = w3*8 + g*4;
        gemmN<4,16>(acc, p.w_bq + (size_t)f0*16*512, l, as);
#pragma unroll
        for (int jj = 0; jj < 2; ++jj) {
          const int j = (w3*4 + g*2 + jj)*16 + fl;
          const float bm = p.b_bq[j], bs = p.b_bq[1024 + j];
#pragma unroll
          for (int rr = 0; rr < 4; ++rr) {
            const int row = fg*4 + rr;
            const float mean = acc[2*jj][rr] + bm;
            const float sd = sp_f(acc[2*jj+1][rr] + bs) + 0.1f;
            const float bl = mean + sd * nbt[(size_t)row*1024 + j];
            obt[(size_t)row*1024 + j] = bl;
            sB[aoff(row, j, 1024)] = f2b(bl);
          }
        }
      }
    }
    __syncthreads();
    // ---- S5: shq = relu(bel @ Webq_lo' + obs_c[t]): 2 frags/wave ----
    {
      auto ab = [&](int c){ return *(const short8*)(sB + aoff(fl, c + fg*8, 1024)); };
      const bf16* oc = p.obs_c + (size_t)(t*512 + rbase)*512;
      f32x4 acc[2] = {};
      const int f0 = w3*2;
      gemmN<2,32>(acc, p.w_ebq + (size_t)f0*32*512, l, ab);
#pragma unroll
      for (int q = 0; q < 2; ++q) {
        const int col = (f0+q)*16 + fl;
#pragma unroll
        for (int rr = 0; rr < 4; ++rr) {
          const int row = fg*4 + rr;
          float v = acc[q][rr] + b2f(oc[(size_t)row*512 + col]);
          sD[aoff(row, 512 + col, 1024)] = f2b(v > 0.f ? v : 0.f);
        }
      }
    }
    __syncthreads();
    // ---- S6: q head (paired Wsq'): 2 frags/wave (1 jt) ----
    {
      auto ax = [&](int c){ return *(const short8*)(sD + aoff(fl, 512 + c + fg*8, 1024)); };
      const float* nqt = p.nq + (size_t)(t*512 + rbase)*256;
      float* qm = p.o_qm  + (size_t)(t*512 + rbase)*256;
      float* qs = p.o_qsd + (size_t)(t*512 + rbase)*256;
      float* qt = p.o_qst + (size_t)(t*512 + rbase)*256;
      const float* ntp = p.nonterm + (size_t)t*512 + rbase;
      f32x4 acc[2] = {};
      const int f0 = w3*2;
      gemmN<2,16>(acc, p.w_sq + (size_t)f0*16*512, l, ax);
      const int j = w3*16 + fl;
      const float bm = p.b_sq[j], bs = p.b_sq[256 + j];
#pragma unroll
      for (int rr = 0; rr < 4; ++rr) {
        const int row = fg*4 + rr;
        const float mean = acc[0][rr] + bm;
        const float sd = sp_f(acc[1][rr] + bs) + 0.1f;
        const float q = mean + sd * nqt[(size_t)row*256 + j];
        qm[(size_t)row*256 + j] = mean;
        qs[(size_t)row*256 + j] = sd;
        qt[(size_t)row*256 + j] = q;
        sR[aoff(row, j, 320)] = f2b(q * ntp[row]);
      }
    }
    __syncthreads();
  }
}

// ===== wide-kernel helpers (R6/R7/R8-proven, unchanged) =====
__device__ __forceinline__ int lds_off(int row, int slot){ return row*64 + ((slot ^ (row & 7)) << 3); }

__device__ __forceinline__ void glds_tile(const bf16* base, int ld, bf16* buf, int w, int l) {
  const int rsub = l >> 3;
  const int slot = (l & 7) ^ rsub;
  const bf16* src = base + (size_t)(w*32 + rsub)*ld + slot*8;
#pragma unroll
  for (int i = 0; i < 4; ++i)
    __builtin_amdgcn_global_load_lds((const __attribute__((address_space(1))) void*)(src + (size_t)(i*8)*ld),
                                     (__attribute__((address_space(3))) void*)(buf + (w*32 + i*8)*64),
                                     16, 0, 0);
}
__device__ __forceinline__ void glds_tile64(const bf16* base, int ld, bf16* buf, int w, int l) {
  const int rsub = l >> 3;
  const int slot = (l & 7) ^ rsub;
  const bf16* src = base + (size_t)(w*16 + rsub)*ld + slot*8;
#pragma unroll
  for (int i = 0; i < 2; ++i)
    __builtin_amdgcn_global_load_lds((const __attribute__((address_space(1))) void*)(src + (size_t)(i*8)*ld),
                                     (__attribute__((address_space(3))) void*)(buf + (w*16 + i*8)*64),
                                     16, 0, 0);
}

__device__ __forceinline__ void mfma_tiles(f32x4 acc[4][4], const bf16* bA, const bf16* bB,
                                           int wm, int wn, int fl, int fg) {
#pragma unroll
  for (int ks = 0; ks < 2; ++ks) {
    short8 af[4], bfr[4];
#pragma unroll
    for (int i = 0; i < 4; ++i)
      af[i] = *(const short8*)(bA + lds_off(wm*64 + i*16 + fl, ks*4 + fg));
#pragma unroll
    for (int i = 0; i < 4; ++i)
      bfr[i] = *(const short8*)(bB + lds_off(wn*64 + i*16 + fl, ks*4 + fg));
#pragma unroll
    for (int mf = 0; mf < 4; ++mf)
#pragma unroll
      for (int nf = 0; nf < 4; ++nf)
        asm("v_mfma_f32_16x16x32_bf16 %0, %1, %2, %0"
            : "+v"(acc[mf][nf]) : "v"(af[mf]), "v"(bfr[nf]));
  }
}

template<bool RELU>
__device__ void wide_f32_gemm(const float* A, int lda, const bf16* Bw, int ldb, int K,
                              const float* bias, bf16* dst, int ldc) {
  __shared__ bf16 sA0[8192];
  __shared__ bf16 sB0[8192];
  const int tid = threadIdx.x, l = tid & 63, w = tid >> 6;
  const int wm = w >> 1, wn = w & 1, fl = l & 15, fg = l >> 4;
  const int rb = ((int)blockIdx.x >> 2) << 7, nt = blockIdx.x & 3;
  f32x4 acc[4][4] = {};
#pragma unroll 1
  for (int ki = 0; ki < (K >> 6); ++ki) {
    const int k0 = ki << 6;
    glds_tile(Bw + (size_t)(nt*128)*ldb + k0, ldb, sB0, w, l);
#pragma unroll
    for (int i = 0; i < 4; ++i) {
      const int sid = tid + (i << 8);
      const int row = sid >> 3, s = sid & 7;
      const float* src = A + (size_t)(rb + row)*lda + k0 + s*8;
      float4 a = ((const float4*)src)[0], b = ((const float4*)src)[1];
      bf16 t8[8] __attribute__((aligned(16)));
      t8[0]=f2b(a.x); t8[1]=f2b(a.y); t8[2]=f2b(a.z); t8[3]=f2b(a.w);
      t8[4]=f2b(b.x); t8[5]=f2b(b.y); t8[6]=f2b(b.z); t8[7]=f2b(b.w);
      *(short8*)(sA0 + lds_off(row, s)) = *(const short8*)t8;
    }
    asm volatile("s_waitcnt vmcnt(0) lgkmcnt(0)" ::: "memory");
    __builtin_amdgcn_s_barrier();
    mfma_tiles(acc, sA0, sB0, wm, wn, fl, fg);
    __builtin_amdgcn_s_barrier();
  }
#pragma unroll
  for (int mf = 0; mf < 4; ++mf)
#pragma unroll
    for (int nf = 0; nf < 4; ++nf) {
      const int col = nt*128 + wn*64 + nf*16 + fl;
      const float bv = bias[col];
#pragma unroll
      for (int r = 0; r < 4; ++r) {
        const int row = rb + wm*64 + mf*16 + fg*4 + r;
        float v = acc[mf][nf][r] + bv;
        if (RELU) v = v > 0.f ? v : 0.f;
        dst[(size_t)row*ldc + col] = f2b(v);
      }
    }
}

__global__ __launch_bounds__(256) void obsc_k(const float* obs, const bf16* webqh,
                                              const float* b_ebq, bf16* obs_c) {
  wide_f32_gemm<false>(obs, 1024, webqh, 1024, 1024, b_ebq, obs_c, 512);
}
__global__ __launch_bounds__(256) void shp_k(const float* bel, const bf16* webp,
                                             const float* b_ebp, bf16* shp) {
  wide_f32_gemm<true>(bel, 1024, webp, 1024, 1024, b_ebp, shp, 512);
}

__global__ __launch_bounds__(256) void phead_k(const bf16* shp, const bf16* wsp,
    const float* b_sp, const float* np, float* o_pm, float* o_psd, float* o_pst) {
  __shared__ bf16 stA[64*64];
  __shared__ bf16 stB[128*64];
  __shared__ float stash[64*256];
  const int tid = threadIdx.x, l = tid & 63, w = tid >> 6;
  const int wm = w >> 1, wn = w & 1, fl = l & 15, fg = l >> 4;
  const int R0 = blockIdx.x * 64;
#pragma unroll 1
  for (int nt = 0; nt < 4; ++nt) {
    f32x4 acc[2][4] = {};
#pragma unroll 1
    for (int kc = 0; kc < 8; ++kc) {
      glds_tile64(shp + (size_t)R0*512 + kc*64, 512, stA, w, l);
      glds_tile(wsp + (size_t)(nt*128)*512 + kc*64, 512, stB, w, l);
      asm volatile("s_waitcnt vmcnt(0)" ::: "memory");
      __builtin_amdgcn_s_barrier();
#pragma unroll
      for (int ks = 0; ks < 2; ++ks) {
        short8 af[2], bfr[4];
#pragma unroll
        for (int mf = 0; mf < 2; ++mf)
          af[mf] = *(const short8*)(stA + lds_off(wm*32 + mf*16 + fl, ks*4 + fg));
#pragma unroll
        for (int nf = 0; nf < 4; ++nf)
          bfr[nf] = *(const short8*)(stB + lds_off(wn*64 + nf*16 + fl, ks*4 + fg));
#pragma unroll
        for (int mf = 0; mf < 2; ++mf)
#pragma unroll
          for (int nf = 0; nf < 4; ++nf)
            asm("v_mfma_f32_16x16x32_bf16 %0, %1, %2, %0"
                : "+v"(acc[mf][nf]) : "v"(af[mf]), "v"(bfr[nf]));
      }
      __builtin_amdgcn_s_barrier();
    }
#pragma unroll
    for (int mf = 0; mf < 2; ++mf)
#pragma unroll
      for (int gg = 0; gg < 2; ++gg) {
        const int j = nt*64 + (wn*2 + gg)*16 + fl;
        const float bm = b_sp[j], bs = b_sp[256 + j];
#pragma unroll
        for (int rr = 0; rr < 4; ++rr) {
          const int rl = wm*32 + mf*16 + fg*4 + rr;
          const float mean = acc[mf][2*gg][rr] + bm;
          const float sd = sp_f(acc[mf][2*gg+1][rr] + bs) + 0.1f;
          o_pm [(size_t)(R0+rl)*256 + j] = mean;
          o_psd[(size_t)(R0+rl)*256 + j] = sd;
          stash[rl*256 + j] = mean + sd * np[(size_t)(R0+rl)*256 + j];
        }
      }
  }
  __syncthreads();
#pragma unroll 1
  for (int i = tid; i < 4096; i += 256) {
    const int r = i >> 6, c4 = (i & 63) << 2;
    *(float4*)(o_pst + (size_t)(R0+r)*256 + c4) = *(const float4*)(stash + r*256 + c4);
  }
}

// ===== prep: fragment-packing kernels (R8-proven, unchanged) =====
__global__ __launch_bounds__(256) void k_pack(const float* __restrict__ src, bf16* __restrict__ dst,
    int NF, int KC, int Ksrc, int ldsrc, int rowoff, int pair, int halfN) {
  const int idx = blockIdx.x*256 + threadIdx.x;
  if (idx >= NF*KC*64) return;
  const int lane = idx & 63, kc = (idx >> 6) % KC, fi = idx / (64*KC);
  int col;
  if (pair) { const int jt = fi >> 1, pp = fi & 1; col = pp*halfN + jt*16 + (lane & 15); }
  else col = fi*16 + (lane & 15);
  const int kb = kc*32 + (lane >> 4)*8;
  bf16 t8[8] __attribute__((aligned(16)));
#pragma unroll
  for (int e = 0; e < 8; ++e) {
    const int k = kb + e;
    t8[e] = f2b(k < Ksrc ? src[(size_t)col*ldsrc + rowoff + k] : 0.f);
  }
  *(short8*)(dst + (size_t)idx*8) = *(const short8*)t8;
}

__global__ __launch_bounds__(256) void k_gru_pack6(const float* __restrict__ Wih,
    const float* __restrict__ Whh, bf16* __restrict__ dst) {
  const int idx = blockIdx.x*256 + threadIdx.x;
  if (idx >= 786432) return;
  const int lane = idx & 63;
  const int rest = idx >> 6;
  const int slot = rest % 6;
  const int tkc  = rest / 6;
  const int kc = tkc & 31, jt = tkc >> 5;
  const int j = jt*16 + (lane & 15);
  const int kb = kc*32 + (lane >> 4)*8;
  const float* src;
  if (slot == 0)      src = Wih + (size_t)j*1024;
  else if (slot == 1) src = Wih + (size_t)(1024+j)*1024;
  else if (slot == 2) src = Wih + (size_t)(2048+j)*1024;
  else if (slot == 3) src = Whh + (size_t)j*1024;
  else if (slot == 4) src = Whh + (size_t)(1024+j)*1024;
  else                src = Whh + (size_t)(2048+j)*1024;
  bf16 t8[8] __attribute__((aligned(16)));
#pragma unroll
  for (int e = 0; e < 8; ++e) t8[e] = f2b(src[kb + e]);
  *(short8*)(dst + (size_t)idx*8) = *(const short8*)t8;
}

__global__ __launch_bounds__(256) void k_cvt8(const float* __restrict__ s, bf16* __restrict__ d, int n8) {
  const int i = blockIdx.x*256 + threadIdx.x;
  if (i >= n8) return;
  float4 a = ((const float4*)s)[i*2], b = ((const float4*)s)[i*2+1];
  bf16 t8[8] __attribute__((aligned(16)));
  t8[0]=f2b(a.x); t8[1]=f2b(a.y); t8[2]=f2b(a.z); t8[3]=f2b(a.w);
  t8[4]=f2b(b.x); t8[5]=f2b(b.y); t8[6]=f2b(b.z); t8[7]=f2b(b.w);
  ((short8*)d)[i] = *(const short8*)t8;
}
__global__ __launch_bounds__(256) void k_cvthalf(const float* __restrict__ s, bf16* __restrict__ d) {
  const int i = blockIdx.x*256 + threadIdx.x;
  if (i >= 65536) return;
  const int r = i >> 7, c8 = (i & 127)*8;
  const float* sp2 = s + (size_t)r*2048 + 1024 + c8;
  float4 a = ((const float4*)sp2)[0], b = ((const float4*)sp2)[1];
  bf16 t8[8] __attribute__((aligned(16)));
  t8[0]=f2b(a.x); t8[1]=f2b(a.y); t8[2]=f2b(a.z); t8[3]=f2b(a.w);
  t8[4]=f2b(b.x); t8[5]=f2b(b.y); t8[6]=f2b(b.z); t8[7]=f2b(b.w);
  *(short8*)(d + (size_t)i*8) = *(const short8*)t8;
}
__global__ __launch_bounds__(256) void k_pair(const float* __restrict__ src, bf16* __restrict__ dst,
                                              int halfN, int n) {
  const int idx = blockIdx.x*256 + threadIdx.x;
  if (idx >= n) return;
  const int rp = idx >> 7;
  const int c4 = (idx & 127) << 2;
  const int nt = rp >> 7, id = rp & 127;
  const int pb = (id >> 5) & 3, comp = (id >> 4) & 1, fl2 = id & 15;
  const int j = nt*64 + pb*16 + fl2;
  const int srow = comp*halfN + j;
  float4 v = *(const float4*)(src + (size_t)srow*512 + c4);
  bf16 t4[4] __attribute__((aligned(8)));
  t4[0]=f2b(v.x); t4[1]=f2b(v.y); t4[2]=f2b(v.z); t4[3]=f2b(v.w);
  *(uint2*)(dst + (size_t)rp*512 + c4) = *(const uint2*)t4;
}
__global__ __launch_bounds__(256) void k_bg(const float* b_ih, const float* b_hh, float* bg) {
  const int i = blockIdx.x*256 + threadIdx.x;
  if (i >= 4096) return;
  const int g = i >> 10, j = i & 1023;
  float v;
  if (g == 0) v = b_ih[j] + b_hh[j];
  else if (g == 1) v = b_ih[1024+j] + b_hh[1024+j];
  else if (g == 2) v = b_ih[2048+j];
  else v = b_hh[2048+j];
  bg[i] = v;
}

extern "C" void kernel_launch(void* const* d_in, const int* in_sizes, int n_in,
                              void* d_out, int out_size, void* d_ws, size_t ws_size,
                              hipStream_t stream) {
  const float* prev_state   = (const float*)d_in[0];
  const float* prev_belief  = (const float*)d_in[1];
  const float* actions      = (const float*)d_in[2];
  const float* observations = (const float*)d_in[3];
  const float* nonterm      = (const float*)d_in[4];
  const float* noise_belief = (const float*)d_in[5];
  const float* noise_prior  = (const float*)d_in[6];
  const float* noise_post   = (const float*)d_in[7];
  const float* W_sa  = (const float*)d_in[8];  const float* b_sa  = (const float*)d_in[9];
  const float* W_ih  = (const float*)d_in[10]; const float* b_ih  = (const float*)d_in[11];
  const float* W_hh  = (const float*)d_in[12]; const float* b_hh  = (const float*)d_in[13];
  const float* W_eb  = (const float*)d_in[14]; const float* b_eb  = (const float*)d_in[15];
  const float* W_bq  = (const float*)d_in[16]; const float* b_bq  = (const float*)d_in[17];
  const float* W_ebp = (const float*)d_in[18]; const float* b_ebp = (const float*)d_in[19];
  const float* W_sp  = (const float*)d_in[20]; const float* b_sp  = (const float*)d_in[21];
  const float* W_ebq = (const float*)d_in[22]; const float* b_ebq = (const float*)d_in[23];
  const float* W_sq  = (const float*)d_in[24]; const float* b_sq  = (const float*)d_in[25];

  float* out = (float*)d_out;
  char* ws = (char*)d_ws;

  float* bg   = (float*)ws;                  // [4096] f32
  bf16* wb    = (bf16*)(ws + 16384);
  bf16* w_sa  = wb;                          // 64f x 10kc   =   327,680
  bf16* w_gru = wb + 327680;                 // 64jt x 32kc x 6 = 6,291,456
  bf16* w_eb  = wb + 6619136;                // 32f x 32kc   =   524,288
  bf16* w_bq  = wb + 7143424;                // 128f x 16kc  = 1,048,576
  bf16* w_ebq = wb + 8192000;                // 32f x 32kc   =   524,288
  bf16* w_sq  = wb + 8716288;                // 32f x 16kc   =   262,144
  bf16* w_ebqh= wb + 8978432;                // old [512][1024] 524,288
  bf16* w_ebp = wb + 9502720;                // old [512][1024] 524,288
  bf16* w_sp  = wb + 10027008;               // old-pair [512][512] 262,144

  float* o_bel = out;
  float* o_pst = out + 33554432;
  float* o_pm  = out + 41943040;
  float* o_psd = out + 50331648;
  float* o_qst = out + 58720256;
  float* o_qm  = out + 67108864;
  float* o_qsd = out + 75497472;
  bf16* obs_c = (bf16*)o_pm;    // [32768][512] bf16 (dead until p_mean written)
  bf16* shp   = (bf16*)o_pst;   // [32768][512] bf16 (overwritten row-locally)

  // ---- prep ----
  k_bg       <<<16,   256, 0, stream>>>(b_ih, b_hh, bg);
  k_pack     <<<160,  256, 0, stream>>>(W_sa, w_sa, 64, 10, 288, 288, 0, 0, 0);
  k_gru_pack6<<<3072, 256, 0, stream>>>(W_ih, W_hh, w_gru);
  k_pack     <<<256,  256, 0, stream>>>(W_eb, w_eb, 32, 32, 1024, 1024, 0, 0, 0);
  k_pack     <<<512,  256, 0, stream>>>(W_bq, w_bq, 128, 16, 512, 512, 0, 1, 1024);
  k_pack     <<<256,  256, 0, stream>>>(W_ebq, w_ebq, 32, 32, 1024, 2048, 0, 0, 0);
  k_pack     <<<128,  256, 0, stream>>>(W_sq, w_sq, 32, 16, 512, 512, 0, 1, 256);
  k_cvthalf  <<<256,  256, 0, stream>>>(W_ebq, w_ebqh);
  k_cvt8     <<<256,  256, 0, stream>>>(W_ebp, w_ebp, 65536);
  k_pair     <<<256,  256, 0, stream>>>(W_sp, w_sp, 256, 65536);

  // ---- prologue: obs contribution ----
  obsc_k<<<1024, 256, 0, stream>>>(observations, w_ebqh, b_ebq, obs_c);

  // ---- scan: 32 zero-sync blocks x 1024 threads (16 waves) ----
  SP p;
  p.prev_state = prev_state; p.prev_belief = prev_belief; p.actions = actions;
  p.nonterm = nonterm; p.nb = noise_belief; p.nq = noise_post;
  p.w_sa = w_sa; p.w_gru = w_gru; p.w_eb = w_eb; p.w_bq = w_bq; p.w_ebq = w_ebq; p.w_sq = w_sq;
  p.bg = bg; p.b_sa = b_sa; p.b_eb = b_eb; p.b_bq = b_bq; p.b_sq = b_sq;
  p.obs_c = obs_c;
  p.o_bel = o_bel; p.o_qst = o_qst; p.o_qm = o_qm; p.o_qsd = o_qsd;
  scan_k<<<32, 1024, 0, stream>>>(p);

  // ---- prior branch ----
  shp_k  <<<1024, 256, 0, stream>>>(o_bel, w_ebp, b_ebp, shp);
  phead_k<<<512,  256, 0, stream>>>(shp, w_sp, b_sp, noise_prior, o_pm, o_psd, o_pst);
}